// Round 9
// baseline (405.000 us; speedup 1.0000x reference)
//
#include <hip/hip_runtime.h>
#include <cstdint>
#include <cstddef>

#define B_ 4
#define S_ 2048
#define D_ 512
#define H_ 8
#define DK_ 64
#define DFF_ 2048

using s16x8  = __attribute__((ext_vector_type(8))) short;
using bf16x8 = __attribute__((ext_vector_type(8))) __bf16;
using f32x4  = __attribute__((ext_vector_type(4))) float;

__device__ __forceinline__ short f2bf(float f) {
  unsigned u = __builtin_bit_cast(unsigned, f);
  u += 0x7FFFu + ((u >> 16) & 1u);
  return (short)(u >> 16);
}
__device__ __forceinline__ float bf2f(short s) {
  unsigned u = ((unsigned)(unsigned short)s) << 16;
  return __builtin_bit_cast(float, u);
}

// async global->LDS, 16 B per lane. LDS dest = wave-uniform base + lane*16.
__device__ __forceinline__ void gl2lds16(const void* g, void* l) {
  __builtin_amdgcn_global_load_lds(
      (const __attribute__((address_space(1))) void*)g,
      (__attribute__((address_space(3))) void*)l, 16, 0, 0);
}

// ---------------- fused f32 -> bf16 conversion (all tensors, one launch) ----------------
__global__ __launch_bounds__(256)
void cvt_all(const float* __restrict__ x, const float* __restrict__ Wq,
             const float* __restrict__ Wk, const float* __restrict__ Wv,
             const float* __restrict__ Wp, const float* __restrict__ W1,
             const float* __restrict__ W2,
             short* __restrict__ xb, short* __restrict__ wqkv,
             short* __restrict__ wp, short* __restrict__ w1, short* __restrict__ w2) {
  int blk = blockIdx.x;
  const float* src; short* dst; int off;
  if (blk < 4096)      { src = x;  dst = xb;            off = blk; }
  else if (blk < 4352) { src = Wq; dst = wqkv;          off = blk - 4096; }
  else if (blk < 4608) { src = Wk; dst = wqkv + 262144; off = blk - 4352; }
  else if (blk < 4864) { src = Wv; dst = wqkv + 524288; off = blk - 4608; }
  else if (blk < 5120) { src = Wp; dst = wp;            off = blk - 4864; }
  else if (blk < 6144) { src = W1; dst = w1;            off = blk - 5120; }
  else                 { src = W2; dst = w2;            off = blk - 6144; }
  int i = (off * 256 + threadIdx.x) * 4;
  float4 v = *(const float4*)(src + i);
  *(short4*)(dst + i) = make_short4(f2bf(v.x), f2bf(v.y), f2bf(v.z), f2bf(v.w));
}

// ---------------- mask: single-kernel detect + convert ----------------
__global__ __launch_bounds__(256)
void mask_all(const void* __restrict__ m, float* __restrict__ mb) {
  __shared__ unsigned red[4];
  const unsigned* mw = (const unsigned*)m;
  const int t = threadIdx.x;
  unsigned v = 0;
#pragma unroll
  for (int i = 0; i < 8; ++i) v |= mw[t + i * 256];
#pragma unroll
  for (int s = 1; s < 64; s <<= 1) v |= __shfl_xor(v, s);
  if ((t & 63) == 0) red[t >> 6] = v;
  __syncthreads();
  unsigned f = red[0] | red[1] | red[2] | red[3];
  int i = blockIdx.x * 256 + t;
  int val;
  if ((f & ~1u) == 0u)            val = ((const int*)m)[i];
  else if (f == 0x3F800000u)      val = (((const float*)m)[i] != 0.0f);
  else                            val = ((const unsigned char*)m)[i];
  mb[i] = val ? 0.0f : -100.0f;
}

// ---------------- unified bf16 MFMA GEMM: 256t, 128x128 tile, BK=64, XOR swizzle ----------------
template <int MODE>
__global__ __launch_bounds__(256)
void gemm_bt(const short* __restrict__ A, const short* __restrict__ B,
             int M, int N, int K,
             const float* __restrict__ aux1,
             void* __restrict__ out0, void* __restrict__ out1, void* __restrict__ out2) {
  __shared__ alignas(16) short As[128][64];
  __shared__ alignas(16) short Bs[128][64];

  const int tid  = threadIdx.x;
  const int lane = tid & 63;
  const int wave = tid >> 6;
  const int quad = lane >> 4;
  const int l16  = lane & 15;
  const int wm   = (wave >> 1) * 64;
  const int wn   = (wave & 1) * 64;
  const int bm   = blockIdx.x * 128;
  const int bn   = blockIdx.y * 128;
  const int Kh   = K / gridDim.z;
  const int koff = blockIdx.z * Kh;

  const int srow8 = lane >> 3;   // row within an 8-row staging chunk
  const int pb    = lane & 7;    // physical 16B block within 128B row

  f32x4 acc[4][4] = {};

  for (int k0 = 0; k0 < Kh; k0 += 64) {
#pragma unroll
    for (int i = 0; i < 4; ++i) {
      const int rr = wave * 32 + i * 8 + srow8;      // tile row 0..127
      const int cb = pb ^ (rr & 7);                  // logical 16B block (swizzle)
      gl2lds16(A + (size_t)(bm + rr) * K + koff + k0 + cb * 8, &As[wave * 32 + i * 8][0]);
      gl2lds16(B + (size_t)(bn + rr) * K + koff + k0 + cb * 8, &Bs[wave * 32 + i * 8][0]);
    }
    __syncthreads();

#pragma unroll
    for (int c = 0; c < 2; ++c) {
      bf16x8 a[4], b[4];
#pragma unroll
      for (int i = 0; i < 4; ++i) {
        const int row = wm + i * 16 + l16;
        const int pba = (c * 4 + quad) ^ (row & 7);
        a[i] = __builtin_bit_cast(bf16x8, *(const s16x8*)&As[row][pba * 8]);
      }
#pragma unroll
      for (int j = 0; j < 4; ++j) {
        const int row = wn + j * 16 + l16;
        const int pbb = (c * 4 + quad) ^ (row & 7);
        b[j] = __builtin_bit_cast(bf16x8, *(const s16x8*)&Bs[row][pbb * 8]);
      }
#pragma unroll
      for (int i = 0; i < 4; ++i)
#pragma unroll
        for (int j = 0; j < 4; ++j)
          acc[i][j] = __builtin_amdgcn_mfma_f32_16x16x32_bf16(a[i], b[j], acc[i][j], 0, 0, 0);
    }
    __syncthreads();
  }

#pragma unroll
  for (int i = 0; i < 4; ++i) {
    const int m0 = bm + wm + i * 16 + quad * 4;
#pragma unroll
    for (int j = 0; j < 4; ++j) {
      const int n = bn + wn + j * 16 + l16;
      if constexpr (MODE == 0) {
        const int bb = m0 >> 11, ss0 = m0 & 2047;
        if (n < 512) {  // Q^T -> [B,H,64,S], scaled 1/8
          short4 pk = make_short4(f2bf(acc[i][j][0] * 0.125f), f2bf(acc[i][j][1] * 0.125f),
                                  f2bf(acc[i][j][2] * 0.125f), f2bf(acc[i][j][3] * 0.125f));
          *(short4*)((short*)out0 +
              ((((size_t)bb * H_ + (n >> 6)) * 64 + (n & 63)) * S_ + ss0)) = pk;
        } else if (n >= 1024) {  // V^T -> [B,H,64,S]
          const int nn = n - 1024;
          short4 pk = make_short4(f2bf(acc[i][j][0]), f2bf(acc[i][j][1]),
                                  f2bf(acc[i][j][2]), f2bf(acc[i][j][3]));
          *(short4*)((short*)out2 +
              ((((size_t)bb * H_ + (nn >> 6)) * 64 + (nn & 63)) * S_ + ss0)) = pk;
        } else {  // K -> [B,H,S,64]
          const int nn = n - 512;
          const size_t rowb = ((size_t)bb * H_ + (nn >> 6)) * S_ + ss0;
#pragma unroll
          for (int rr = 0; rr < 4; ++rr)
            ((short*)out1)[(rowb + rr) * 64 + (nn & 63)] = f2bf(acc[i][j][rr]);
        }
      } else if constexpr (MODE == 1) {  // f32 split-K partial
        float* dst = (float*)out0 + (size_t)blockIdx.z * M * N;
#pragma unroll
        for (int rr = 0; rr < 4; ++rr)
          dst[(size_t)(m0 + rr) * N + n] = acc[i][j][rr];
      } else {  // MODE 2: gelu(acc + bias) -> bf16
#pragma unroll
        for (int rr = 0; rr < 4; ++rr) {
          float t = acc[i][j][rr] + aux1[n];
          float gl = 0.5f * t * (1.0f + erff(t * 0.70710678118f));
          ((short*)out0)[(size_t)(m0 + rr) * N + n] = f2bf(gl);
        }
      }
    }
  }
}

// ---------------- MFMA flash attention v6 ----------------
// Direct-global K/V fragments: QK^T B-operand (K[key][d], 16B contiguous) and
// PV B-operand (V^T[d][key], 16B contiguous) load straight from global; all 4
// waves read IDENTICAL addresses -> L1 broadcast (tile 16KB << 32KB L1).
// This removes K/V LDS staging + frag reads AND both per-tile barriers (Ps is
// per-wave) -> barrier-free K-loop, loads pipeline across iterations.
// Ps uses an XOR block swizzle (block ^= row&7) -> write conflicts ~2-way (free).
// Fixed-max softmax; P truncated to bf16, li accumulates truncated values.
__global__ __launch_bounds__(256, 2)
void flash_attn_mfma(const short* __restrict__ QTg, const short* __restrict__ Kb,
                     const short* __restrict__ Vtg, const float* __restrict__ maskbias,
                     short* __restrict__ ctxb) {
  __shared__ alignas(16) short Ps[4][32][72];
  __shared__ alignas(16) float mrow[S_];

  const int b = blockIdx.z, h = blockIdx.y;
  const int tid = threadIdx.x;
  const int w = tid >> 6, lane = tid & 63;
  const int quad = lane >> 4, l16 = lane & 15;
  const size_t base  = ((size_t)(b * H_ + h)) * S_ * DK_;  // K   [B,H,S,64]
  const size_t baseT = ((size_t)(b * H_ + h)) * DK_ * S_;  // Q^T/V^T [B,H,64,S]
  const int q0 = blockIdx.x * 128;

  {
    const float4* mp = (const float4*)(maskbias + (size_t)b * S_);
    ((float4*)mrow)[tid]       = mp[tid];
    ((float4*)mrow)[tid + 256] = mp[tid + 256];
  }
  __syncthreads();  // the only barrier: fence mrow

  // Q fragments from Q^T: 2 strips x 2 k-halves, gathered once per block
  bf16x8 qa[2][2];
#pragma unroll
  for (int st = 0; st < 2; ++st) {
    const int q = q0 + w * 32 + st * 16 + l16;
#pragma unroll
    for (int c = 0; c < 2; ++c) {
      s16x8 t;
#pragma unroll
      for (int j = 0; j < 8; ++j)
        t[j] = QTg[baseT + (size_t)(c * 32 + quad * 8 + j) * S_ + q];
      qa[st][c] = __builtin_bit_cast(bf16x8, t);
    }
  }

  f32x4 Oc[2][4] = {};
  float li[2][4] = {};
  const int swz = l16 & 7;                 // read-side row&7 (row = st*16+l16)
  const short* kfrag = Kb  + base  + quad * 8;          // + (t0+jt*16+l16)*64 + c*32
  const short* vfrag = Vtg + baseT + quad * 8;          // + (dt*16+l16)*S + t0 + c*32

  for (int t0 = 0; t0 < S_; t0 += 64) {
    // S = Q K^T : K fragments direct from global (L1-broadcast across waves)
    f32x4 sc[2][4] = {};
#pragma unroll
    for (int c = 0; c < 2; ++c) {
#pragma unroll
      for (int jt = 0; jt < 4; ++jt) {
        bf16x8 kb = __builtin_bit_cast(bf16x8,
            *(const s16x8*)(kfrag + (size_t)(t0 + jt * 16 + l16) * 64 + c * 32));
        sc[0][jt] = __builtin_amdgcn_mfma_f32_16x16x32_bf16(qa[0][c], kb, sc[0][jt], 0, 0, 0);
        sc[1][jt] = __builtin_amdgcn_mfma_f32_16x16x32_bf16(qa[1][c], kb, sc[1][jt], 0, 0, 0);
      }
    }

    float mb4[4];
#pragma unroll
    for (int jt = 0; jt < 4; ++jt) mb4[jt] = mrow[t0 + jt * 16 + l16];
#pragma unroll
    for (int st = 0; st < 2; ++st) {
#pragma unroll
      for (int jt = 0; jt < 4; ++jt) {
#pragma unroll
        for (int rr = 0; rr < 4; ++rr) {
          float p = __expf(sc[st][jt][rr] + mb4[jt]);
          unsigned u = __builtin_bit_cast(unsigned, p) & 0xFFFF0000u;
          li[st][rr] += __builtin_bit_cast(float, u);
          const int row = st * 16 + quad * 4 + rr;
          const int blk = (jt * 2 + (l16 >> 3)) ^ (row & 7);   // XOR swizzle
          Ps[w][row][blk * 8 + (l16 & 7)] = (short)(u >> 16);
        }
      }
    }

    // O += P V : V^T fragments direct from global; Ps read back (same-wave order)
#pragma unroll
    for (int c = 0; c < 2; ++c) {
      bf16x8 pa0 = __builtin_bit_cast(bf16x8,
          *(const s16x8*)&Ps[w][l16][(((c * 4 + quad) ^ swz)) * 8]);
      bf16x8 pa1 = __builtin_bit_cast(bf16x8,
          *(const s16x8*)&Ps[w][16 + l16][(((c * 4 + quad) ^ swz)) * 8]);
#pragma unroll
      for (int dt = 0; dt < 4; ++dt) {
        bf16x8 vb = __builtin_bit_cast(bf16x8,
            *(const s16x8*)(vfrag + (size_t)(dt * 16 + l16) * S_ + t0 + c * 32));
        Oc[0][dt] = __builtin_amdgcn_mfma_f32_16x16x32_bf16(pa0, vb, Oc[0][dt], 0, 0, 0);
        Oc[1][dt] = __builtin_amdgcn_mfma_f32_16x16x32_bf16(pa1, vb, Oc[1][dt], 0, 0, 0);
      }
    }
  }

#pragma unroll
  for (int st = 0; st < 2; ++st) {
#pragma unroll
    for (int rr = 0; rr < 4; ++rr) {
      float l = li[st][rr];
#pragma unroll
      for (int m = 1; m < 16; m <<= 1) l += __shfl_xor(l, m);
      float inv = 1.f / l;
      const size_t row = (size_t)b * S_ + q0 + w * 32 + st * 16 + quad * 4 + rr;
#pragma unroll
      for (int dt = 0; dt < 4; ++dt)
        ctxb[row * (H_ * DK_) + h * 64 + dt * 16 + l16] = f2bf(Oc[st][dt][rr] * inv);
    }
  }
}

// ---------------- fused split-K reduce + LayerNorm (one wave per token) ----------------
__global__ __launch_bounds__(256)
void ln_fused(const float* __restrict__ p0, const float* __restrict__ p1,
              const float* __restrict__ xres, const short* __restrict__ hres,
              const float* __restrict__ bias,
              const float* __restrict__ g, const float* __restrict__ bb,
              float* __restrict__ out32, short* __restrict__ outb) {
  const int wave = threadIdx.x >> 6, lane = threadIdx.x & 63;
  const int token = blockIdx.x * 4 + wave;
  const size_t off = (size_t)token * D_;
  const int c = lane * 8;

  float v[8];
  {
    float4 a0 = *(const float4*)(p0 + off + c);
    float4 a1 = *(const float4*)(p0 + off + c + 4);
    float4 b0 = *(const float4*)(p1 + off + c);
    float4 b1 = *(const float4*)(p1 + off + c + 4);
    v[0]=a0.x+b0.x; v[1]=a0.y+b0.y; v[2]=a0.z+b0.z; v[3]=a0.w+b0.w;
    v[4]=a1.x+b1.x; v[5]=a1.y+b1.y; v[6]=a1.z+b1.z; v[7]=a1.w+b1.w;
  }
  if (xres) {
    float4 x0 = *(const float4*)(xres + off + c);
    float4 x1 = *(const float4*)(xres + off + c + 4);
    v[0]+=x0.x; v[1]+=x0.y; v[2]+=x0.z; v[3]+=x0.w;
    v[4]+=x1.x; v[5]+=x1.y; v[6]+=x1.z; v[7]+=x1.w;
  }
  if (hres) {
    short4 h0 = *(const short4*)(hres + off + c);
    short4 h1 = *(const short4*)(hres + off + c + 4);
    v[0]+=bf2f(h0.x); v[1]+=bf2f(h0.y); v[2]+=bf2f(h0.z); v[3]+=bf2f(h0.w);
    v[4]+=bf2f(h1.x); v[5]+=bf2f(h1.y); v[6]+=bf2f(h1.z); v[7]+=bf2f(h1.w);
  }
  if (bias) {
    float4 c0 = *(const float4*)(bias + c);
    float4 c1 = *(const float4*)(bias + c + 4);
    v[0]+=c0.x; v[1]+=c0.y; v[2]+=c0.z; v[3]+=c0.w;
    v[4]+=c1.x; v[5]+=c1.y; v[6]+=c1.z; v[7]+=c1.w;
  }

  float sum = 0.f;
#pragma unroll
  for (int i = 0; i < 8; ++i) sum += v[i];
#pragma unroll
  for (int m = 1; m < 64; m <<= 1) sum += __shfl_xor(sum, m);
  float mu = sum * (1.0f / D_);
  float vs = 0.f;
#pragma unroll
  for (int i = 0; i < 8; ++i) { v[i] -= mu; vs += v[i] * v[i]; }
#pragma unroll
  for (int m = 1; m < 64; m <<= 1) vs += __shfl_xor(vs, m);
  float rstd = rsqrtf(vs * (1.0f / D_) + 1e-5f);
#pragma unroll
  for (int i = 0; i < 8; ++i) {
    float val = v[i] * rstd * g[c + i] + bb[c + i];
    if (out32) out32[off + c + i] = val;
    if (outb)  outb[off + c + i] = f2bf(val);
  }
}

// ---------------- workspace layout (bytes) ----------------
constexpr size_t OFF_XB   = 0;                       // [8192,512] bf16
constexpr size_t OFF_WQKV = 8388608;                 // [1536,512] bf16 (Wq|Wk|Wv)
constexpr size_t OFF_WP   = 9961472;                 // [512,512] bf16
constexpr size_t OFF_W1   = 10485760;                // [2048,512] bf16
constexpr size_t OFF_W2   = 12582912;                // [512,2048] bf16
constexpr size_t OFF_QT   = 14680064;                // [B,H,64,S] bf16 (transposed!)
constexpr size_t OFF_K    = 23068672;                // [B,H,S,64] bf16
constexpr size_t OFF_VT   = 31457280;                // [B,H,64,S] bf16 (transposed!)
constexpr size_t OFF_CTX  = 39845888;                // [8192,512] bf16
constexpr size_t OFF_P0   = 48234496;                // [8192,512] f32 split-K partial 0
constexpr size_t OFF_P1   = 65011712;                // [8192,512] f32 split-K partial 1
constexpr size_t OFF_HB   = 81788928;                // [8192,512] bf16 (LN1 out)
constexpr size_t OFF_FF1  = 14680064;                // [8192,2048] bf16 (reuses QT/K/VT/CTX)
constexpr size_t OFF_MB   = 90177536;                // [8192] f32 mask bias
constexpr size_t WS_NEED  = 90210304;

extern "C" void kernel_launch(void* const* d_in, const int* in_sizes, int n_in,
                              void* d_out, int out_size, void* d_ws, size_t ws_size,
                              hipStream_t stream) {
  if (ws_size < WS_NEED) return;

  const float* x    = (const float*)d_in[0];
  const void*  msk  = d_in[1];
  const float* Wq   = (const float*)d_in[2];
  const float* Wk   = (const float*)d_in[3];
  const float* Wv   = (const float*)d_in[4];
  const float* Wp   = (const float*)d_in[5];
  const float* W1   = (const float*)d_in[6];
  const float* b1   = (const float*)d_in[7];
  const float* W2   = (const float*)d_in[8];
  const float* b2   = (const float*)d_in[9];
  const float* ln1g = (const float*)d_in[10];
  const float* ln1b = (const float*)d_in[11];
  const float* ln2g = (const float*)d_in[12];
  const float* ln2b = (const float*)d_in[13];

  char* ws = (char*)d_ws;
  short* xb    = (short*)(ws + OFF_XB);
  short* wqkv  = (short*)(ws + OFF_WQKV);
  short* Wpb   = (short*)(ws + OFF_WP);
  short* W1b   = (short*)(ws + OFF_W1);
  short* W2b   = (short*)(ws + OFF_W2);
  short* QTb   = (short*)(ws + OFF_QT);
  short* Kbh   = (short*)(ws + OFF_K);
  short* VTb   = (short*)(ws + OFF_VT);
  short* ctxb  = (short*)(ws + OFF_CTX);
  float* p0    = (float*)(ws + OFF_P0);   // split-K partials (P0|P1 contiguous)
  short* hb    = (short*)(ws + OFF_HB);
  short* ff1b  = (short*)(ws + OFF_FF1);
  float* mbias = (float*)(ws + OFF_MB);

  // mask: fused detect + convert (one dispatch)
  mask_all<<<32, 256, 0, stream>>>(msk, mbias);

  // all f32->bf16 conversions in one launch
  cvt_all<<<7168, 256, 0, stream>>>(x, Wq, Wk, Wv, Wp, W1, W2,
                                    xb, wqkv, Wpb, W1b, W2b);

  // fused QKV projection: N=1536 (Q^T scaled 0.125; V^T; K row-major)
  gemm_bt<0><<<dim3(64, 12, 1), 256, 0, stream>>>(xb, wqkv, 8192, 1536, 512,
                                                  nullptr, QTb, Kbh, VTb);

  // attention (MFMA flash v6: direct-global K/V, barrier-free)
  flash_attn_mfma<<<dim3(S_ / 128, H_, B_), 256, 0, stream>>>(QTb, Kbh, VTb, mbias, ctxb);

  // output projection, split-K=2 -> f32 partials (reduce+residual in LN1)
  gemm_bt<1><<<dim3(64, 4, 2), 256, 0, stream>>>(ctxb, Wpb, 8192, 512, 512,
                                                 nullptr, p0, nullptr, nullptr);

  // LN1: LN(p0 + p1 + x) -> h (bf16)
  ln_fused<<<2048, 256, 0, stream>>>(p0, p0 + (size_t)8192 * 512, x, nullptr, nullptr,
                                     ln1g, ln1b, nullptr, hb);

  // FF1: gelu(h @ W1^T + b1) -> bf16
  gemm_bt<2><<<dim3(64, 16, 1), 256, 0, stream>>>(hb, W1b, 8192, 2048, 512,
                                                  b1, ff1b, nullptr, nullptr);

  // FF2: split-K=2 -> f32 partials (reduce+bias+residual in LN2)
  gemm_bt<1><<<dim3(64, 4, 2), 256, 0, stream>>>(ff1b, W2b, 8192, 512, 2048,
                                                 nullptr, p0, nullptr, nullptr);

  // LN2: LN(p0 + p1 + b2 + h) -> out (f32)
  ln_fused<<<2048, 256, 0, stream>>>(p0, p0 + (size_t)8192 * 512, nullptr, hb, b2,
                                     ln2g, ln2b, (float*)d_out, nullptr);
}

// Round 10
// 314.742 us; speedup vs baseline: 1.2868x; 1.2868x over previous
//
#include <hip/hip_runtime.h>
#include <cstdint>
#include <cstddef>

#define B_ 4
#define S_ 2048
#define D_ 512
#define H_ 8
#define DK_ 64
#define DFF_ 2048

using s16x8  = __attribute__((ext_vector_type(8))) short;
using bf16x8 = __attribute__((ext_vector_type(8))) __bf16;
using f32x4  = __attribute__((ext_vector_type(4))) float;

__device__ __forceinline__ short f2bf(float f) {
  unsigned u = __builtin_bit_cast(unsigned, f);
  u += 0x7FFFu + ((u >> 16) & 1u);
  return (short)(u >> 16);
}
__device__ __forceinline__ float bf2f(short s) {
  unsigned u = ((unsigned)(unsigned short)s) << 16;
  return __builtin_bit_cast(float, u);
}

// async global->LDS, 16 B per lane. LDS dest = wave-uniform base + lane*16.
__device__ __forceinline__ void gl2lds16(const void* g, void* l) {
  __builtin_amdgcn_global_load_lds(
      (const __attribute__((address_space(1))) void*)g,
      (__attribute__((address_space(3))) void*)l, 16, 0, 0);
}

// ---------------- fused f32 -> bf16 conversion (all tensors, one launch) ----------------
__global__ __launch_bounds__(256)
void cvt_all(const float* __restrict__ x, const float* __restrict__ Wq,
             const float* __restrict__ Wk, const float* __restrict__ Wv,
             const float* __restrict__ Wp, const float* __restrict__ W1,
             const float* __restrict__ W2,
             short* __restrict__ xb, short* __restrict__ wqkv,
             short* __restrict__ wp, short* __restrict__ w1, short* __restrict__ w2) {
  int blk = blockIdx.x;
  const float* src; short* dst; int off;
  if (blk < 4096)      { src = x;  dst = xb;            off = blk; }
  else if (blk < 4352) { src = Wq; dst = wqkv;          off = blk - 4096; }
  else if (blk < 4608) { src = Wk; dst = wqkv + 262144; off = blk - 4352; }
  else if (blk < 4864) { src = Wv; dst = wqkv + 524288; off = blk - 4608; }
  else if (blk < 5120) { src = Wp; dst = wp;            off = blk - 4864; }
  else if (blk < 6144) { src = W1; dst = w1;            off = blk - 5120; }
  else                 { src = W2; dst = w2;            off = blk - 6144; }
  int i = (off * 256 + threadIdx.x) * 4;
  float4 v = *(const float4*)(src + i);
  *(short4*)(dst + i) = make_short4(f2bf(v.x), f2bf(v.y), f2bf(v.z), f2bf(v.w));
}

// ---------------- unified bf16 MFMA GEMM: 256t, 128x128 tile, BK=64, XOR swizzle ----------------
template <int MODE>
__global__ __launch_bounds__(256)
void gemm_bt(const short* __restrict__ A, const short* __restrict__ B,
             int M, int N, int K,
             const float* __restrict__ aux1,
             void* __restrict__ out0, void* __restrict__ out1, void* __restrict__ out2) {
  __shared__ alignas(16) short As[128][64];
  __shared__ alignas(16) short Bs[128][64];

  const int tid  = threadIdx.x;
  const int lane = tid & 63;
  const int wave = tid >> 6;
  const int quad = lane >> 4;
  const int l16  = lane & 15;
  const int wm   = (wave >> 1) * 64;
  const int wn   = (wave & 1) * 64;
  const int bm   = blockIdx.x * 128;
  const int bn   = blockIdx.y * 128;
  const int Kh   = K / gridDim.z;
  const int koff = blockIdx.z * Kh;

  const int srow8 = lane >> 3;   // row within an 8-row staging chunk
  const int pb    = lane & 7;    // physical 16B block within 128B row

  f32x4 acc[4][4] = {};

  for (int k0 = 0; k0 < Kh; k0 += 64) {
#pragma unroll
    for (int i = 0; i < 4; ++i) {
      const int rr = wave * 32 + i * 8 + srow8;      // tile row 0..127
      const int cb = pb ^ (rr & 7);                  // logical 16B block (swizzle)
      gl2lds16(A + (size_t)(bm + rr) * K + koff + k0 + cb * 8, &As[wave * 32 + i * 8][0]);
      gl2lds16(B + (size_t)(bn + rr) * K + koff + k0 + cb * 8, &Bs[wave * 32 + i * 8][0]);
    }
    __syncthreads();

#pragma unroll
    for (int c = 0; c < 2; ++c) {
      bf16x8 a[4], b[4];
#pragma unroll
      for (int i = 0; i < 4; ++i) {
        const int row = wm + i * 16 + l16;
        const int pba = (c * 4 + quad) ^ (row & 7);
        a[i] = __builtin_bit_cast(bf16x8, *(const s16x8*)&As[row][pba * 8]);
      }
#pragma unroll
      for (int j = 0; j < 4; ++j) {
        const int row = wn + j * 16 + l16;
        const int pbb = (c * 4 + quad) ^ (row & 7);
        b[j] = __builtin_bit_cast(bf16x8, *(const s16x8*)&Bs[row][pbb * 8]);
      }
#pragma unroll
      for (int i = 0; i < 4; ++i)
#pragma unroll
        for (int j = 0; j < 4; ++j)
          acc[i][j] = __builtin_amdgcn_mfma_f32_16x16x32_bf16(a[i], b[j], acc[i][j], 0, 0, 0);
    }
    __syncthreads();
  }

#pragma unroll
  for (int i = 0; i < 4; ++i) {
    const int m0 = bm + wm + i * 16 + quad * 4;
#pragma unroll
    for (int j = 0; j < 4; ++j) {
      const int n = bn + wn + j * 16 + l16;
      if constexpr (MODE == 0) {
        const int bb = m0 >> 11, ss0 = m0 & 2047;
        if (n < 512) {  // Q^T -> [B,H,64,S], scaled 1/8
          short4 pk = make_short4(f2bf(acc[i][j][0] * 0.125f), f2bf(acc[i][j][1] * 0.125f),
                                  f2bf(acc[i][j][2] * 0.125f), f2bf(acc[i][j][3] * 0.125f));
          *(short4*)((short*)out0 +
              ((((size_t)bb * H_ + (n >> 6)) * 64 + (n & 63)) * S_ + ss0)) = pk;
        } else if (n >= 1024) {  // V^T -> [B,H,64,S]
          const int nn = n - 1024;
          short4 pk = make_short4(f2bf(acc[i][j][0]), f2bf(acc[i][j][1]),
                                  f2bf(acc[i][j][2]), f2bf(acc[i][j][3]));
          *(short4*)((short*)out2 +
              ((((size_t)bb * H_ + (nn >> 6)) * 64 + (nn & 63)) * S_ + ss0)) = pk;
        } else {  // K -> [B,H,S,64]
          const int nn = n - 512;
          const size_t rowb = ((size_t)bb * H_ + (nn >> 6)) * S_ + ss0;
#pragma unroll
          for (int rr = 0; rr < 4; ++rr)
            ((short*)out1)[(rowb + rr) * 64 + (nn & 63)] = f2bf(acc[i][j][rr]);
        }
      } else if constexpr (MODE == 1) {  // f32 split-K partial
        float* dst = (float*)out0 + (size_t)blockIdx.z * M * N;
#pragma unroll
        for (int rr = 0; rr < 4; ++rr)
          dst[(size_t)(m0 + rr) * N + n] = acc[i][j][rr];
      } else {  // MODE 2: gelu(acc + bias) -> bf16
#pragma unroll
        for (int rr = 0; rr < 4; ++rr) {
          float t = acc[i][j][rr] + aux1[n];
          float gl = 0.5f * t * (1.0f + erff(t * 0.70710678118f));
          ((short*)out0)[(size_t)(m0 + rr) * N + n] = f2bf(gl);
        }
      }
    }
  }
}

// ---------------- MFMA flash attention v7 = v5 + fused mask + swizzled Ps ----------------
// v5 structure (measured plateau 75us): 4 waves, 128 q/block, 2 strips/wave,
// LDS-staged K/V with register prefetch (R9 proved direct-global K/V is 2x
// WORSE: per-wave VMEM re-fetch + exposed vmcnt latency).
// New: (a) mask dtype-detect + bias row computed in preamble (drops a dispatch),
// (b) Ps stored with XOR block swizzle in unpadded [64] rows (write: blk =
// (jt*2+(l16>>3))^(row&7); read: (c*4+quad)^(l16&7)) -> uniform banks.
__global__ __launch_bounds__(256)
void flash_attn_mfma(const short* __restrict__ QTg, const short* __restrict__ Kb,
                     const short* __restrict__ Vtg, const void* __restrict__ mraw,
                     short* __restrict__ ctxb) {
  __shared__ alignas(16) short Ks[64][72];
  __shared__ alignas(16) short Vt[64][72];
  __shared__ alignas(16) short Ps[4][32][64];
  __shared__ alignas(16) float mrow[S_];
  __shared__ unsigned red[4];

  const int b = blockIdx.z, h = blockIdx.y;
  const int tid = threadIdx.x;
  const int w = tid >> 6, lane = tid & 63;
  const int quad = lane >> 4, l16 = lane & 15;
  const size_t base  = ((size_t)(b * H_ + h)) * S_ * DK_;  // K   [B,H,S,64]
  const size_t baseT = ((size_t)(b * H_ + h)) * DK_ * S_;  // Q^T/V^T [B,H,64,S]
  const int q0 = blockIdx.x * 128;

  // ---- mask: detect dtype (OR of first 2048 words), build bias row b ----
  {
    const unsigned* mw = (const unsigned*)mraw;
    unsigned v = 0;
#pragma unroll
    for (int i = 0; i < 8; ++i) v |= mw[tid + i * 256];
#pragma unroll
    for (int s = 1; s < 64; s <<= 1) v |= __shfl_xor(v, s);
    if (lane == 0) red[w] = v;
    __syncthreads();
    unsigned f = red[0] | red[1] | red[2] | red[3];
#pragma unroll
    for (int i = 0; i < 8; ++i) {
      int idx = tid + i * 256;          // 0..2047
      int gidx = b * S_ + idx;
      int val;
      if ((f & ~1u) == 0u)            val = ((const int*)mraw)[gidx];
      else if (f == 0x3F800000u)      val = (((const float*)mraw)[gidx] != 0.0f);
      else                            val = ((const unsigned char*)mraw)[gidx];
      mrow[idx] = val ? 0.0f : -100.0f;
    }
  }

  // Q fragments from Q^T: 2 strips x 2 k-halves, gathered once per block
  bf16x8 qa[2][2];
#pragma unroll
  for (int st = 0; st < 2; ++st) {
    const int q = q0 + w * 32 + st * 16 + l16;
#pragma unroll
    for (int c = 0; c < 2; ++c) {
      s16x8 t;
#pragma unroll
      for (int j = 0; j < 8; ++j)
        t[j] = QTg[baseT + (size_t)(c * 32 + quad * 8 + j) * S_ + q];
      qa[st][c] = __builtin_bit_cast(bf16x8, t);
    }
  }

  f32x4 Oc[2][4] = {};
  float li[2][4] = {};
  const int swz = l16 & 7;

  const int r = tid >> 2, c16 = (tid & 3) * 16;
  const short* kp = Kb  + base  + (size_t)r * 64 + c16;
  const short* vp = Vtg + baseT + (size_t)r * S_ + c16;

  // preload tile 0
  s16x8 kr0 = *(const s16x8*)(kp);
  s16x8 kr1 = *(const s16x8*)(kp + 8);
  s16x8 vr0 = *(const s16x8*)(vp);
  s16x8 vr1 = *(const s16x8*)(vp + 8);

  for (int t0 = 0; t0 < S_; t0 += 64) {
    __syncthreads();  // prev tile consumers done (also fences mrow on iter 0)
    *(s16x8*)&Ks[r][c16]     = kr0;
    *(s16x8*)&Ks[r][c16 + 8] = kr1;
    *(s16x8*)&Vt[r][c16]     = vr0;
    *(s16x8*)&Vt[r][c16 + 8] = vr1;
    __syncthreads();

    if (t0 + 64 < S_) {  // prefetch next tile during compute
      kr0 = *(const s16x8*)(kp + (size_t)(t0 + 64) * 64);
      kr1 = *(const s16x8*)(kp + (size_t)(t0 + 64) * 64 + 8);
      vr0 = *(const s16x8*)(vp + t0 + 64);
      vr1 = *(const s16x8*)(vp + t0 + 64 + 8);
    }

    // S = Q K^T
    f32x4 sc[2][4] = {};
#pragma unroll
    for (int c = 0; c < 2; ++c) {
#pragma unroll
      for (int jt = 0; jt < 4; ++jt) {
        bf16x8 kb = __builtin_bit_cast(bf16x8,
            *(const s16x8*)&Ks[jt * 16 + l16][c * 32 + quad * 8]);
        sc[0][jt] = __builtin_amdgcn_mfma_f32_16x16x32_bf16(qa[0][c], kb, sc[0][jt], 0, 0, 0);
        sc[1][jt] = __builtin_amdgcn_mfma_f32_16x16x32_bf16(qa[1][c], kb, sc[1][jt], 0, 0, 0);
      }
    }

    float mb4[4];
#pragma unroll
    for (int jt = 0; jt < 4; ++jt) mb4[jt] = mrow[t0 + jt * 16 + l16];
#pragma unroll
    for (int st = 0; st < 2; ++st) {
#pragma unroll
      for (int jt = 0; jt < 4; ++jt) {
#pragma unroll
        for (int rr = 0; rr < 4; ++rr) {
          float p = __expf(sc[st][jt][rr] + mb4[jt]);
          unsigned u = __builtin_bit_cast(unsigned, p) & 0xFFFF0000u;
          li[st][rr] += __builtin_bit_cast(float, u);
          const int row = st * 16 + quad * 4 + rr;
          const int blk = (jt * 2 + (l16 >> 3)) ^ (row & 7);   // XOR swizzle
          Ps[w][row][blk * 8 + (l16 & 7)] = (short)(u >> 16);
        }
      }
    }

    // O += P V (Ps read back with matching swizzle: row&7 == l16&7)
#pragma unroll
    for (int c = 0; c < 2; ++c) {
      bf16x8 pa0 = __builtin_bit_cast(bf16x8,
          *(const s16x8*)&Ps[w][l16][((c * 4 + quad) ^ swz) * 8]);
      bf16x8 pa1 = __builtin_bit_cast(bf16x8,
          *(const s16x8*)&Ps[w][16 + l16][((c * 4 + quad) ^ swz) * 8]);
#pragma unroll
      for (int dt = 0; dt < 4; ++dt) {
        bf16x8 vb = __builtin_bit_cast(bf16x8,
            *(const s16x8*)&Vt[dt * 16 + l16][c * 32 + quad * 8]);
        Oc[0][dt] = __builtin_amdgcn_mfma_f32_16x16x32_bf16(pa0, vb, Oc[0][dt], 0, 0, 0);
        Oc[1][dt] = __builtin_amdgcn_mfma_f32_16x16x32_bf16(pa1, vb, Oc[1][dt], 0, 0, 0);
      }
    }
  }

#pragma unroll
  for (int st = 0; st < 2; ++st) {
#pragma unroll
    for (int rr = 0; rr < 4; ++rr) {
      float l = li[st][rr];
#pragma unroll
      for (int m = 1; m < 16; m <<= 1) l += __shfl_xor(l, m);
      float inv = 1.f / l;
      const size_t row = (size_t)b * S_ + q0 + w * 32 + st * 16 + quad * 4 + rr;
#pragma unroll
      for (int dt = 0; dt < 4; ++dt)
        ctxb[row * (H_ * DK_) + h * 64 + dt * 16 + l16] = f2bf(Oc[st][dt][rr] * inv);
    }
  }
}

// ---------------- fused split-K reduce + LayerNorm (one wave per token) ----------------
__global__ __launch_bounds__(256)
void ln_fused(const float* __restrict__ p0, const float* __restrict__ p1,
              const float* __restrict__ xres, const short* __restrict__ hres,
              const float* __restrict__ bias,
              const float* __restrict__ g, const float* __restrict__ bb,
              float* __restrict__ out32, short* __restrict__ outb) {
  const int wave = threadIdx.x >> 6, lane = threadIdx.x & 63;
  const int token = blockIdx.x * 4 + wave;
  const size_t off = (size_t)token * D_;
  const int c = lane * 8;

  float v[8];
  {
    float4 a0 = *(const float4*)(p0 + off + c);
    float4 a1 = *(const float4*)(p0 + off + c + 4);
    float4 b0 = *(const float4*)(p1 + off + c);
    float4 b1 = *(const float4*)(p1 + off + c + 4);
    v[0]=a0.x+b0.x; v[1]=a0.y+b0.y; v[2]=a0.z+b0.z; v[3]=a0.w+b0.w;
    v[4]=a1.x+b1.x; v[5]=a1.y+b1.y; v[6]=a1.z+b1.z; v[7]=a1.w+b1.w;
  }
  if (xres) {
    float4 x0 = *(const float4*)(xres + off + c);
    float4 x1 = *(const float4*)(xres + off + c + 4);
    v[0]+=x0.x; v[1]+=x0.y; v[2]+=x0.z; v[3]+=x0.w;
    v[4]+=x1.x; v[5]+=x1.y; v[6]+=x1.z; v[7]+=x1.w;
  }
  if (hres) {
    short4 h0 = *(const short4*)(hres + off + c);
    short4 h1 = *(const short4*)(hres + off + c + 4);
    v[0]+=bf2f(h0.x); v[1]+=bf2f(h0.y); v[2]+=bf2f(h0.z); v[3]+=bf2f(h0.w);
    v[4]+=bf2f(h1.x); v[5]+=bf2f(h1.y); v[6]+=bf2f(h1.z); v[7]+=bf2f(h1.w);
  }
  if (bias) {
    float4 c0 = *(const float4*)(bias + c);
    float4 c1 = *(const float4*)(bias + c + 4);
    v[0]+=c0.x; v[1]+=c0.y; v[2]+=c0.z; v[3]+=c0.w;
    v[4]+=c1.x; v[5]+=c1.y; v[6]+=c1.z; v[7]+=c1.w;
  }

  float sum = 0.f;
#pragma unroll
  for (int i = 0; i < 8; ++i) sum += v[i];
#pragma unroll
  for (int m = 1; m < 64; m <<= 1) sum += __shfl_xor(sum, m);
  float mu = sum * (1.0f / D_);
  float vs = 0.f;
#pragma unroll
  for (int i = 0; i < 8; ++i) { v[i] -= mu; vs += v[i] * v[i]; }
#pragma unroll
  for (int m = 1; m < 64; m <<= 1) vs += __shfl_xor(vs, m);
  float rstd = rsqrtf(vs * (1.0f / D_) + 1e-5f);
#pragma unroll
  for (int i = 0; i < 8; ++i) {
    float val = v[i] * rstd * g[c + i] + bb[c + i];
    if (out32) out32[off + c + i] = val;
    if (outb)  outb[off + c + i] = f2bf(val);
  }
}

// ---------------- workspace layout (bytes) ----------------
constexpr size_t OFF_XB   = 0;                       // [8192,512] bf16
constexpr size_t OFF_WQKV = 8388608;                 // [1536,512] bf16 (Wq|Wk|Wv)
constexpr size_t OFF_WP   = 9961472;                 // [512,512] bf16
constexpr size_t OFF_W1   = 10485760;                // [2048,512] bf16
constexpr size_t OFF_W2   = 12582912;                // [512,2048] bf16
constexpr size_t OFF_QT   = 14680064;                // [B,H,64,S] bf16 (transposed!)
constexpr size_t OFF_K    = 23068672;                // [B,H,S,64] bf16
constexpr size_t OFF_VT   = 31457280;                // [B,H,64,S] bf16 (transposed!)
constexpr size_t OFF_CTX  = 39845888;                // [8192,512] bf16
constexpr size_t OFF_P0   = 48234496;                // [8192,512] f32 split-K partial 0
constexpr size_t OFF_P1   = 65011712;                // [8192,512] f32 split-K partial 1
constexpr size_t OFF_HB   = 81788928;                // [8192,512] bf16 (LN1 out)
constexpr size_t OFF_FF1  = 14680064;                // [8192,2048] bf16 (reuses QT/K/VT/CTX)
constexpr size_t WS_NEED  = 90177536;

extern "C" void kernel_launch(void* const* d_in, const int* in_sizes, int n_in,
                              void* d_out, int out_size, void* d_ws, size_t ws_size,
                              hipStream_t stream) {
  if (ws_size < WS_NEED) return;

  const float* x    = (const float*)d_in[0];
  const void*  msk  = d_in[1];
  const float* Wq   = (const float*)d_in[2];
  const float* Wk   = (const float*)d_in[3];
  const float* Wv   = (const float*)d_in[4];
  const float* Wp   = (const float*)d_in[5];
  const float* W1   = (const float*)d_in[6];
  const float* b1   = (const float*)d_in[7];
  const float* W2   = (const float*)d_in[8];
  const float* b2   = (const float*)d_in[9];
  const float* ln1g = (const float*)d_in[10];
  const float* ln1b = (const float*)d_in[11];
  const float* ln2g = (const float*)d_in[12];
  const float* ln2b = (const float*)d_in[13];

  char* ws = (char*)d_ws;
  short* xb    = (short*)(ws + OFF_XB);
  short* wqkv  = (short*)(ws + OFF_WQKV);
  short* Wpb   = (short*)(ws + OFF_WP);
  short* W1b   = (short*)(ws + OFF_W1);
  short* W2b   = (short*)(ws + OFF_W2);
  short* QTb   = (short*)(ws + OFF_QT);
  short* Kbh   = (short*)(ws + OFF_K);
  short* VTb   = (short*)(ws + OFF_VT);
  short* ctxb  = (short*)(ws + OFF_CTX);
  float* p0    = (float*)(ws + OFF_P0);   // split-K partials (P0|P1 contiguous)
  short* hb    = (short*)(ws + OFF_HB);
  short* ff1b  = (short*)(ws + OFF_FF1);

  // all f32->bf16 conversions in one launch
  cvt_all<<<7168, 256, 0, stream>>>(x, Wq, Wk, Wv, Wp, W1, W2,
                                    xb, wqkv, Wpb, W1b, W2b);

  // fused QKV projection: N=1536 (Q^T scaled 0.125; V^T; K row-major)
  gemm_bt<0><<<dim3(64, 12, 1), 256, 0, stream>>>(xb, wqkv, 8192, 1536, 512,
                                                  nullptr, QTb, Kbh, VTb);

  // attention (MFMA flash v7: v5 + fused mask + swizzled Ps)
  flash_attn_mfma<<<dim3(S_ / 128, H_, B_), 256, 0, stream>>>(QTb, Kbh, VTb, msk, ctxb);

  // output projection, split-K=2 -> f32 partials (reduce+residual in LN1)
  gemm_bt<1><<<dim3(64, 4, 2), 256, 0, stream>>>(ctxb, Wpb, 8192, 512, 512,
                                                 nullptr, p0, nullptr, nullptr);

  // LN1: LN(p0 + p1 + x) -> h (bf16)
  ln_fused<<<2048, 256, 0, stream>>>(p0, p0 + (size_t)8192 * 512, x, nullptr, nullptr,
                                     ln1g, ln1b, nullptr, hb);

  // FF1: gelu(h @ W1^T + b1) -> bf16
  gemm_bt<2><<<dim3(64, 16, 1), 256, 0, stream>>>(hb, W1b, 8192, 2048, 512,
                                                  b1, ff1b, nullptr, nullptr);

  // FF2: split-K=2 -> f32 partials (reduce+bias+residual in LN2)
  gemm_bt<1><<<dim3(64, 4, 2), 256, 0, stream>>>(ff1b, W2b, 8192, 512, 2048,
                                                 nullptr, p0, nullptr, nullptr);

  // LN2: LN(p0 + p1 + b2 + h) -> out (f32)
  ln_fused<<<2048, 256, 0, stream>>>(p0, p0 + (size_t)8192 * 512, nullptr, hb, b2,
                                     ln2g, ln2b, (float*)d_out, nullptr);
}